// Round 1
// 859.933 us; speedup vs baseline: 1.0407x; 1.0407x over previous
//
#include <hip/hip_runtime.h>
#include <stdint.h>
#include <stddef.h>

// Problem constants
#define N_ROWS 32768
#define D_IN   3000
#define KPAD   3072   // D_IN padded to multiple of 64 (zero pad)
#define H0     1024
#define H1     256
#define NCLUST 20

typedef __attribute__((ext_vector_type(8))) short short8;   // 8 x bf16 (4 VGPRs)
typedef __attribute__((ext_vector_type(4))) float f32x4;

// fp32 -> bf16 (round-to-nearest-even)
__device__ inline unsigned short f2bf(float f) {
    union { float f; unsigned u; } v; v.f = f;
    unsigned r = v.u + 0x7fffu + ((v.u >> 16) & 1u);
    return (unsigned short)(r >> 16);
}

// async global->LDS, 16B per lane; lds dest is wave-uniform base (+lane*16 implicit)
__device__ inline void async16(const unsigned short* g, unsigned short* l) {
    __builtin_amdgcn_global_load_lds(
        (const __attribute__((address_space(1))) unsigned int*)(g),
        (__attribute__((address_space(3))) unsigned int*)(l),
        16, 0, 0);
}

// ---------------------------------------------------------------------------
// x [32768 x 3000] fp32 -> xb [32768 x 3072] bf16, zero-padded cols 3000..3071
// ---------------------------------------------------------------------------
__global__ __launch_bounds__(256)
void cvt_x(const float* __restrict__ x, unsigned short* __restrict__ xb) {
    int idx = blockIdx.x * 256 + threadIdx.x;     // [0, 32768*384)
    int m  = idx / 384;
    int k8 = idx - m * 384;
    uint4 out;
    if (k8 < 375) {
        const float4 v0 = ((const float4*)x)[(size_t)m * 750 + k8 * 2];
        const float4 v1 = ((const float4*)x)[(size_t)m * 750 + k8 * 2 + 1];
        out.x = ((unsigned)f2bf(v0.x)) | (((unsigned)f2bf(v0.y)) << 16);
        out.y = ((unsigned)f2bf(v0.z)) | (((unsigned)f2bf(v0.w)) << 16);
        out.z = ((unsigned)f2bf(v1.x)) | (((unsigned)f2bf(v1.y)) << 16);
        out.w = ((unsigned)f2bf(v1.z)) | (((unsigned)f2bf(v1.w)) << 16);
    } else {
        out.x = 0u; out.y = 0u; out.z = 0u; out.w = 0u;
    }
    ((uint4*)xb)[(size_t)m * 384 + k8] = out;
}

// ---------------------------------------------------------------------------
// W [rows x cols] fp32 row-major -> outT [cols x rowsPad] bf16 (transposed)
// ---------------------------------------------------------------------------
__global__ __launch_bounds__(256)
void transpose_cvt(const float* __restrict__ W, int rows, int cols, int rowsPad,
                   unsigned short* __restrict__ outT) {
    __shared__ unsigned short tile[32][33];
    const int c0 = blockIdx.x * 32;
    const int r0 = blockIdx.y * 32;
    const int tx = threadIdx.x, ty = threadIdx.y;
    #pragma unroll
    for (int i = 0; i < 4; ++i) {
        int r = r0 + ty + i * 8;
        float v = (r < rows) ? W[(size_t)r * cols + c0 + tx] : 0.0f;
        tile[ty + i * 8][tx] = f2bf(v);
    }
    __syncthreads();
    #pragma unroll
    for (int i = 0; i < 4; ++i) {
        int c = c0 + ty + i * 8;
        outT[(size_t)c * rowsPad + r0 + tx] = tile[tx][ty + i * 8];
    }
}

// ---------------------------------------------------------------------------
// GEMM1: 256x256 tile, BK=64, 512 thr = 8 waves (2M x 4N), wave tile 128x64.
// 8-phase-per-2-K-tiles schedule (T3+T4): per phase {ds_read frag subtile |
// stage one half-tile of tile t+1 | barrier | 16 MFMA (setprio) | barrier}.
// Counted vmcnt(4) at P0/P1/P3 phase ends only (never 0 in main loop):
// per-wave staging is deadline-ordered (P0-need first, P2-need last) so the
// 4 newest outstanding loads are always the not-yet-needed ones.
// LDS XOR swizzle (T2): 16B slot ^= row&7; global_load_lds writes linearly,
// so the swizzle is applied on the *global source address* (rule 21) and on
// the ds_read address. Raw asm s_barrier (memory clobber) avoids the
// compiler's vmcnt(0)-drain that __syncthreads() would force.
// Grid (m,n) transposed: the 4 n-blocks sharing an A-slab have linear ids
// = x mod 8 -> same XCD -> A fetched from HBM once.
// ---------------------------------------------------------------------------
#define BARRIER()  asm volatile("s_barrier" ::: "memory")
#define WAITV(n)   asm volatile("s_waitcnt vmcnt(" #n ")" ::: "memory")

template<int EPILOGUE>
__global__ __launch_bounds__(512, 2)
void gemm256(const unsigned short* __restrict__ A,
             const unsigned short* __restrict__ Bt,
             const float* __restrict__ bias,
             void* __restrict__ Cout, int Nn, int K)
{
    __shared__ unsigned short sA[2][256 * 64];   // 2 x 32 KB
    __shared__ unsigned short sB[2][256 * 64];   // 2 x 32 KB

    const int m0   = blockIdx.x * 256;
    const int n0   = blockIdx.y * 256;
    const int tid  = threadIdx.x;
    const int wave = tid >> 6;
    const int lane = tid & 63;
    const int wm   = wave >> 2;          // 0..1 (M half)
    const int wn   = wave & 3;           // 0..3 (N quarter)

    f32x4 acc[8][4];
    #pragma unroll
    for (int i = 0; i < 8; ++i)
        #pragma unroll
        for (int j = 0; j < 4; ++j) acc[i][j] = (f32x4){0.f, 0.f, 0.f, 0.f};

    // ---- staging geometry: 64 1KB wave-loads per K-tile, 8 per wave ----
    // classes: A-P0d rows {0..63,128..191}, B-P0d rows {wn*64+0..31},
    //          B-P1d rows {wn*64+32..63},   A-P2d rows {64..127,192..255}
    const int rs = lane >> 3;            // row within 8-row segment
    const int ss = (lane & 7) ^ rs;      // pre-swizzled 16B source slot
    const int s0 = wave * 2, s1 = wave * 2 + 1;
    const int RA0a = s0 * 8 + (s0 >> 3) * 64;
    const int RA0b = s1 * 8 + (s1 >> 3) * 64;
    const int RA2a = RA0a + 64, RA2b = RA0b + 64;
    const int RB0a = (s0 >> 2) * 64 + (s0 & 3) * 8;
    const int RB0b = (s1 >> 2) * 64 + (s1 & 3) * 8;
    const int RB1a = RB0a + 32, RB1b = RB0b + 32;

    const unsigned short* gA0a = A + (size_t)(m0 + RA0a + rs) * K + ss * 8;
    const unsigned short* gA0b = A + (size_t)(m0 + RA0b + rs) * K + ss * 8;
    const unsigned short* gA2a = A + (size_t)(m0 + RA2a + rs) * K + ss * 8;
    const unsigned short* gA2b = A + (size_t)(m0 + RA2b + rs) * K + ss * 8;
    const unsigned short* gB0a = Bt + (size_t)(n0 + RB0a + rs) * K + ss * 8;
    const unsigned short* gB0b = Bt + (size_t)(n0 + RB0b + rs) * K + ss * 8;
    const unsigned short* gB1a = Bt + (size_t)(n0 + RB1a + rs) * K + ss * 8;
    const unsigned short* gB1b = Bt + (size_t)(n0 + RB1b + rs) * K + ss * 8;

    // ---- fragment read geometry (swizzled ds_read_b128) ----
    const int u   = lane >> 4;           // 0..3 k-slot group
    const int x   = lane & 7;
    const int sk0 = (u ^ x);             // stored slot for ks=0  ((0*4+u)^x)
    const int sk1 = ((4 + u) ^ x);       // stored slot for ks=1
    const int rA  = wm * 128 + (lane & 15);
    const int rB  = wn * 64  + (lane & 15);

    const int KT = K >> 6;

    // prologue: stage tile 0 into buf 0, full drain once
    async16(gA0a, &sA[0][RA0a * 64]);
    async16(gA0b, &sA[0][RA0b * 64]);
    async16(gB0a, &sB[0][RB0a * 64]);
    async16(gB0b, &sB[0][RB0b * 64]);
    async16(gB1a, &sB[0][RB1a * 64]);
    async16(gB1b, &sB[0][RB1b * 64]);
    async16(gA2a, &sA[0][RA2a * 64]);
    async16(gA2b, &sA[0][RA2b * 64]);
    WAITV(0);
    BARRIER();

    short8 af[4][2], bfr[4][2];

    for (int t = 0; t < KT - 1; ++t) {
        const unsigned short* sAb = sA[t & 1];
        const unsigned short* sBb = sB[t & 1];
        unsigned short* sAn = sA[(t + 1) & 1];
        unsigned short* sBn = sB[(t + 1) & 1];
        const int kn = (t + 1) * 64;

        // ---------------- P0: A mi0-3 + B ni0-1; stage A-P0d(t+1) ----------
        #pragma unroll
        for (int i = 0; i < 4; ++i) {
            af[i][0] = *(const short8*)&sAb[(rA + 16 * i) * 64 + sk0 * 8];
            af[i][1] = *(const short8*)&sAb[(rA + 16 * i) * 64 + sk1 * 8];
        }
        #pragma unroll
        for (int j = 0; j < 2; ++j) {
            bfr[j][0] = *(const short8*)&sBb[(rB + 16 * j) * 64 + sk0 * 8];
            bfr[j][1] = *(const short8*)&sBb[(rB + 16 * j) * 64 + sk1 * 8];
        }
        async16(gA0a + kn, &sAn[RA0a * 64]);
        async16(gA0b + kn, &sAn[RA0b * 64]);
        BARRIER();
        __builtin_amdgcn_s_setprio(1);
        #pragma unroll
        for (int i = 0; i < 4; ++i)
            #pragma unroll
            for (int j = 0; j < 2; ++j) {
                acc[i][j] = __builtin_amdgcn_mfma_f32_16x16x32_bf16(af[i][0], bfr[j][0], acc[i][j], 0, 0, 0);
                acc[i][j] = __builtin_amdgcn_mfma_f32_16x16x32_bf16(af[i][1], bfr[j][1], acc[i][j], 0, 0, 0);
            }
        __builtin_amdgcn_s_setprio(0);
        WAITV(4);
        BARRIER();

        // ---------------- P1: B ni2-3; stage B-P0d(t+1) --------------------
        #pragma unroll
        for (int j = 2; j < 4; ++j) {
            bfr[j][0] = *(const short8*)&sBb[(rB + 16 * j) * 64 + sk0 * 8];
            bfr[j][1] = *(const short8*)&sBb[(rB + 16 * j) * 64 + sk1 * 8];
        }
        async16(gB0a + kn, &sBn[RB0a * 64]);
        async16(gB0b + kn, &sBn[RB0b * 64]);
        BARRIER();
        __builtin_amdgcn_s_setprio(1);
        #pragma unroll
        for (int i = 0; i < 4; ++i)
            #pragma unroll
            for (int j = 2; j < 4; ++j) {
                acc[i][j] = __builtin_amdgcn_mfma_f32_16x16x32_bf16(af[i][0], bfr[j][0], acc[i][j], 0, 0, 0);
                acc[i][j] = __builtin_amdgcn_mfma_f32_16x16x32_bf16(af[i][1], bfr[j][1], acc[i][j], 0, 0, 0);
            }
        __builtin_amdgcn_s_setprio(0);
        WAITV(4);
        BARRIER();

        // ---------------- P2: A mi4-7; stage B-P1d(t+1) --------------------
        #pragma unroll
        for (int i = 0; i < 4; ++i) {
            af[i][0] = *(const short8*)&sAb[(rA + 64 + 16 * i) * 64 + sk0 * 8];
            af[i][1] = *(const short8*)&sAb[(rA + 64 + 16 * i) * 64 + sk1 * 8];
        }
        async16(gB1a + kn, &sBn[RB1a * 64]);
        async16(gB1b + kn, &sBn[RB1b * 64]);
        BARRIER();
        __builtin_amdgcn_s_setprio(1);
        #pragma unroll
        for (int i = 0; i < 4; ++i)
            #pragma unroll
            for (int j = 0; j < 2; ++j) {
                acc[4 + i][j] = __builtin_amdgcn_mfma_f32_16x16x32_bf16(af[i][0], bfr[j][0], acc[4 + i][j], 0, 0, 0);
                acc[4 + i][j] = __builtin_amdgcn_mfma_f32_16x16x32_bf16(af[i][1], bfr[j][1], acc[4 + i][j], 0, 0, 0);
            }
        __builtin_amdgcn_s_setprio(0);
        BARRIER();   // no vmcnt: nothing newly consumed in P3

        // ---------------- P3: stage A-P2d(t+1) -----------------------------
        async16(gA2a + kn, &sAn[RA2a * 64]);
        async16(gA2b + kn, &sAn[RA2b * 64]);
        BARRIER();
        __builtin_amdgcn_s_setprio(1);
        #pragma unroll
        for (int i = 0; i < 4; ++i)
            #pragma unroll
            for (int j = 2; j < 4; ++j) {
                acc[4 + i][j] = __builtin_amdgcn_mfma_f32_16x16x32_bf16(af[i][0], bfr[j][0], acc[4 + i][j], 0, 0, 0);
                acc[4 + i][j] = __builtin_amdgcn_mfma_f32_16x16x32_bf16(af[i][1], bfr[j][1], acc[4 + i][j], 0, 0, 0);
            }
        __builtin_amdgcn_s_setprio(0);
        WAITV(4);
        BARRIER();
    }

    // ---- tail tile KT-1: no staging; full drain once, no barriers needed ----
    WAITV(0);
    BARRIER();
    {
        const unsigned short* sAb = sA[(KT - 1) & 1];
        const unsigned short* sBb = sB[(KT - 1) & 1];
        #pragma unroll
        for (int i = 0; i < 4; ++i) {
            af[i][0] = *(const short8*)&sAb[(rA + 16 * i) * 64 + sk0 * 8];
            af[i][1] = *(const short8*)&sAb[(rA + 16 * i) * 64 + sk1 * 8];
        }
        #pragma unroll
        for (int j = 0; j < 4; ++j) {
            bfr[j][0] = *(const short8*)&sBb[(rB + 16 * j) * 64 + sk0 * 8];
            bfr[j][1] = *(const short8*)&sBb[(rB + 16 * j) * 64 + sk1 * 8];
        }
        #pragma unroll
        for (int i = 0; i < 4; ++i)
            #pragma unroll
            for (int j = 0; j < 4; ++j) {
                acc[i][j] = __builtin_amdgcn_mfma_f32_16x16x32_bf16(af[i][0], bfr[j][0], acc[i][j], 0, 0, 0);
                acc[i][j] = __builtin_amdgcn_mfma_f32_16x16x32_bf16(af[i][1], bfr[j][1], acc[i][j], 0, 0, 0);
            }
        #pragma unroll
        for (int i = 0; i < 4; ++i) {
            af[i][0] = *(const short8*)&sAb[(rA + 64 + 16 * i) * 64 + sk0 * 8];
            af[i][1] = *(const short8*)&sAb[(rA + 64 + 16 * i) * 64 + sk1 * 8];
        }
        #pragma unroll
        for (int i = 0; i < 4; ++i)
            #pragma unroll
            for (int j = 0; j < 4; ++j) {
                acc[4 + i][j] = __builtin_amdgcn_mfma_f32_16x16x32_bf16(af[i][0], bfr[j][0], acc[4 + i][j], 0, 0, 0);
                acc[4 + i][j] = __builtin_amdgcn_mfma_f32_16x16x32_bf16(af[i][1], bfr[j][1], acc[4 + i][j], 0, 0, 0);
            }
    }

    // ---- epilogue. C/D layout: col = lane&15, row = (lane>>4)*4 + reg ----
    const int cr = (lane >> 4) * 4;
    const int cc = lane & 15;
    #pragma unroll
    for (int j = 0; j < 4; ++j) {
        const int col = n0 + wn * 64 + j * 16 + cc;
        const float bv = bias[col];
        #pragma unroll
        for (int i = 0; i < 8; ++i) {
            const int rowBase = m0 + wm * 128 + i * 16 + cr;
            #pragma unroll
            for (int r = 0; r < 4; ++r) {
                float v = acc[i][j][r] + bv;
                if (EPILOGUE == 0) {
                    float s = v / (1.0f + __expf(-v));   // silu
                    ((unsigned short*)Cout)[(size_t)(rowBase + r) * Nn + col] = f2bf(s);
                } else {
                    ((float*)Cout)[(size_t)(rowBase + r) * Nn + col] = v;
                }
            }
        }
    }
}

// ---------------------------------------------------------------------------
// Old 128x256 2-phase kernel, kept for GEMM2 (N=256 -> grid (1,256) fits it)
// ---------------------------------------------------------------------------
template<int EPILOGUE>
__global__ __launch_bounds__(256, 2)
void gemm_tn(const unsigned short* __restrict__ A,
             const unsigned short* __restrict__ Bt,
             const float* __restrict__ bias,
             void* __restrict__ Cout, int Nn, int K)
{
    __shared__ unsigned short sA[2][128 * 32];
    __shared__ unsigned short sB[2][256 * 32];

    const int m0   = blockIdx.y * 128;
    const int n0   = blockIdx.x * 256;
    const int tid  = threadIdx.x;
    const int wave = tid >> 6;
    const int lane = tid & 63;
    const int wm   = wave & 1;
    const int wn   = wave >> 1;

    f32x4 acc[4][8];
    #pragma unroll
    for (int i = 0; i < 4; ++i)
        #pragma unroll
        for (int j = 0; j < 8; ++j)
            acc[i][j] = (f32x4){0.f, 0.f, 0.f, 0.f};

    const int laneRow = lane >> 2;
    const int laneCol = (lane & 3) * 8;
    const unsigned short* gA0 = A  + (size_t)(m0 + wave * 32 + laneRow) * K + laneCol;
    const unsigned short* gA1 = gA0 + (size_t)16 * K;
    const unsigned short* gB0 = Bt + (size_t)(n0 + wave * 64 + laneRow) * K + laneCol;
    const unsigned short* gB1 = gB0 + (size_t)16 * K;
    const unsigned short* gB2 = gB0 + (size_t)32 * K;
    const unsigned short* gB3 = gB0 + (size_t)48 * K;
    const int lAo = wave * 1024;
    const int lBo = wave * 2048;

    const int fa = (wm * 64  + (lane & 15)) * 32 + (lane >> 4) * 8;
    const int fb = (wn * 128 + (lane & 15)) * 32 + (lane >> 4) * 8;

    const int KT = K >> 5;

    {
        async16(gA0, &sA[0][lAo]);
        async16(gA1, &sA[0][lAo + 512]);
        async16(gB0, &sB[0][lBo]);
        async16(gB1, &sB[0][lBo + 512]);
        async16(gB2, &sB[0][lBo + 1024]);
        async16(gB3, &sB[0][lBo + 1536]);
    }

    for (int kt = 0; kt < KT; ++kt) {
        const int buf = kt & 1;
        __syncthreads();
        if (kt + 1 < KT) {
            const int k0 = (kt + 1) << 5;
            const int nb = buf ^ 1;
            async16(gA0 + k0, &sA[nb][lAo]);
            async16(gA1 + k0, &sA[nb][lAo + 512]);
            async16(gB0 + k0, &sB[nb][lBo]);
            async16(gB1 + k0, &sB[nb][lBo + 512]);
            async16(gB2 + k0, &sB[nb][lBo + 1024]);
            async16(gB3 + k0, &sB[nb][lBo + 1536]);
        }
        short8 af[4], bf[8];
        #pragma unroll
        for (int t = 0; t < 4; ++t) af[t] = *(const short8*)&sA[buf][fa + t * 512];
        #pragma unroll
        for (int t = 0; t < 8; ++t) bf[t] = *(const short8*)&sB[buf][fb + t * 512];
        #pragma unroll
        for (int i = 0; i < 4; ++i)
            #pragma unroll
            for (int j = 0; j < 8; ++j)
                acc[i][j] = __builtin_amdgcn_mfma_f32_16x16x32_bf16(
                    af[i], bf[j], acc[i][j], 0, 0, 0);
    }

    const int cr = (lane >> 4) * 4;
    const int cc = lane & 15;
    #pragma unroll
    for (int j = 0; j < 8; ++j) {
        const int col = n0 + wn * 128 + j * 16 + cc;
        const float bv = bias[col];
        #pragma unroll
        for (int i = 0; i < 4; ++i) {
            const int rowBase = m0 + wm * 64 + i * 16 + cr;
            #pragma unroll
            for (int r = 0; r < 4; ++r) {
                float v = acc[i][j][r] + bv;
                if (EPILOGUE == 0) {
                    float s = v / (1.0f + __expf(-v));
                    ((unsigned short*)Cout)[(size_t)(rowBase + r) * Nn + col] = f2bf(s);
                } else {
                    ((float*)Cout)[(size_t)(rowBase + r) * Nn + col] = v;
                }
            }
        }
    }
}

// ---------------------------------------------------------------------------
// Soft-assign: q[n,k] = (1 + ||z_n - c_k||^2)^-1, row-normalized (V=1).
// ---------------------------------------------------------------------------
__global__ __launch_bounds__(256)
void cluster_kernel(const float* __restrict__ z, const float* __restrict__ clusters,
                    float* __restrict__ q) {
    __shared__ float sc[NCLUST * H1];
    const int tid = threadIdx.x;
    for (int i = tid; i < NCLUST * H1; i += 256) sc[i] = clusters[i];
    __syncthreads();

    const int wave = tid >> 6, lane = tid & 63;
    const int row = blockIdx.x * 4 + wave;

    const float4 zv = ((const float4*)(z + (size_t)row * H1))[lane];

    float myq = 0.0f, qsum = 0.0f;
    #pragma unroll
    for (int k = 0; k < NCLUST; ++k) {
        const float4 cv = ((const float4*)(sc + k * H1))[lane];
        float dx = zv.x - cv.x, dy = zv.y - cv.y;
        float dz = zv.z - cv.z, dw = zv.w - cv.w;
        float p = dx * dx + dy * dy + dz * dz + dw * dw;
        #pragma unroll
        for (int s = 32; s >= 1; s >>= 1) p += __shfl_xor(p, s, 64);
        float qk = 1.0f / (1.0f + p);
        qsum += qk;
        myq = (lane == k) ? qk : myq;
    }
    if (lane < NCLUST) q[(size_t)row * NCLUST + lane] = myq / qsum;
}

// ---------------------------------------------------------------------------
extern "C" void kernel_launch(void* const* d_in, const int* in_sizes, int n_in,
                              void* d_out, int out_size, void* d_ws, size_t ws_size,
                              hipStream_t stream) {
    const float* x        = (const float*)d_in[0];
    const float* W1       = (const float*)d_in[1];
    const float* b1       = (const float*)d_in[2];
    const float* W2       = (const float*)d_in[3];
    const float* b2       = (const float*)d_in[4];
    const float* clusters = (const float*)d_in[5];
    float* out = (float*)d_out;   // [32768*256 z fp32][32768*20 q fp32]

    unsigned short* xb  = (unsigned short*)d_ws;                  // 32768*3072 bf16
    unsigned short* w1t = xb  + (size_t)N_ROWS * KPAD;            // 1024*3072 bf16
    unsigned short* w2t = w1t + (size_t)H0 * KPAD;                // 256*1024 bf16
    unsigned short* h   = w2t + (size_t)H1 * H0;                  // 32768*1024 bf16

    // 1) x -> bf16 (padded)
    hipLaunchKernelGGL(cvt_x, dim3((N_ROWS * 384) / 256), dim3(256), 0, stream, x, xb);
    // 2) W1 -> bf16 transposed+padded [1024][3072]
    hipLaunchKernelGGL(transpose_cvt, dim3(H0 / 32, KPAD / 32), dim3(32, 8), 0, stream,
                       W1, D_IN, H0, KPAD, w1t);
    // 3) W2 -> bf16 transposed [256][1024]
    hipLaunchKernelGGL(transpose_cvt, dim3(H1 / 32, H0 / 32), dim3(32, 8), 0, stream,
                       W2, H0, H1, H0, w2t);
    // 4) h = silu(xb @ W1 + b1)  [32768 x 1024] bf16 — 8-phase 256^2 kernel.
    //    grid.x = m so same-A n-blocks land on one XCD (id ≡ x mod 8).
    hipLaunchKernelGGL((gemm256<0>), dim3(N_ROWS / 256, H0 / 256), dim3(512), 0, stream,
                       xb, w1t, b1, (void*)h, H0, KPAD);
    // 5) z = h @ W2 + b2  [32768 x 256] fp32 -> d_out
    hipLaunchKernelGGL((gemm_tn<1>), dim3(H1 / 256, N_ROWS / 128), dim3(256), 0, stream,
                       h, w2t, b2, (void*)out, H1, H0);
    // 6) q soft-assign -> d_out tail
    hipLaunchKernelGGL(cluster_kernel, dim3(N_ROWS / 4), dim3(256), 0, stream,
                       out, clusters, out + (size_t)N_ROWS * H1);
}